// Round 3
// baseline (268.172 us; speedup 1.0000x reference)
//
#include <hip/hip_runtime.h>

#define PLACEHOLDER (-1)
#define TINY_F 1.17549435e-38f
#define MAXS 32
#define SPLIT_G 8
#define SPLIT_R 16

__device__ __forceinline__ void amax_combine(float& bv, int& bi, float v, int i) {
    // jnp.argmax: first occurrence wins ties -> prefer smaller index on equal value
    if (v > bv || (v == bv && i < bi)) { bv = v; bi = i; }
}

__device__ __forceinline__ unsigned long long pack_vi(float v, int i) {
    return ((unsigned long long)__float_as_uint(v) << 32) |
           (unsigned long long)(0xFFFFFFFFu - (unsigned)i);
}

__device__ __forceinline__ int unpack_idx(unsigned long long p) {
    return (int)(0xFFFFFFFFu - (unsigned)(p & 0xFFFFFFFFull));
}

// block-level argmax reduce; result valid on thread 0. All threads must reach it.
__device__ __forceinline__ void block_argmax(float& bv, int& bi) {
    for (int off = 32; off > 0; off >>= 1) {
        float ov = __shfl_down(bv, off, 64);
        int   oi = __shfl_down(bi, off, 64);
        amax_combine(bv, bi, ov, oi);
    }
    __shared__ float sv[8];
    __shared__ int   si[8];
    int lane = threadIdx.x & 63;
    int w    = threadIdx.x >> 6;
    if (lane == 0) { sv[w] = bv; si[w] = bi; }
    __syncthreads();
    if (threadIdx.x == 0) {
        int nw = (blockDim.x + 63) >> 6;
        for (int k = 1; k < nw; ++k) amax_combine(bv, bi, sv[k], si[k]);
    }
}

// One fused kernel. Per row b there are per_row = S*SPLIT_G + SPLIT_R blocks:
//   r in [0, S*SPLIT_G)        : greedy-row target-argmax chunk (active iff is_greedy)
//   r in [S*SPLIT_G, per_row)  : recovered-argmax chunk (active iff !is_greedy & rejected)
// Every block increments ws_cnt[b]; the last one assembles the output row.
__global__ void k_fused(const int* __restrict__ draft_ids,
                        const float* __restrict__ draft_probs,
                        const float* __restrict__ target_probs,
                        const int* __restrict__ bonus,
                        const float* __restrict__ uniform,
                        const float* __restrict__ exp_q,
                        const int* __restrict__ is_greedy,
                        unsigned long long* __restrict__ ws_pk,  // B*S + B
                        unsigned int* __restrict__ ws_cnt,       // B
                        int* __restrict__ ws_fr,                 // B
                        int* __restrict__ out,
                        int B, int S, int V) {
    const int per_row = S * SPLIT_G + SPLIT_R;
    int b = blockIdx.x / per_row;
    int r = blockIdx.x - b * per_row;
    bool greedy = is_greedy[b] != 0;

    if (r < S * SPLIT_G) {
        // ---- greedy-row target argmax ----
        int p = r / SPLIT_G, split = r - (r / SPLIT_G) * SPLIT_G;
        if (greedy && draft_ids[b * S + p] != PLACEHOLDER) {
            int chunk = ((V + SPLIT_G - 1) / SPLIT_G + 3) & ~3;
            int begin = split * chunk;
            int end = begin + chunk; if (end > V) end = V;
            if (begin < end) {
                const float* row = target_probs + (size_t)b * (S + 1) * V + (size_t)p * V;
                float bv = 0.0f; int bi = 0x7fffffff;
                int vend = begin + ((end - begin) & ~3);
                const float4* r4 = (const float4*)row;
                for (int j = (begin >> 2) + threadIdx.x; j < (vend >> 2); j += blockDim.x) {
                    float4 f = r4[j];
                    int base = j << 2;
                    amax_combine(bv, bi, f.x, base);
                    amax_combine(bv, bi, f.y, base + 1);
                    amax_combine(bv, bi, f.z, base + 2);
                    amax_combine(bv, bi, f.w, base + 3);
                }
                for (int j = vend + threadIdx.x; j < end; j += blockDim.x)
                    amax_combine(bv, bi, row[j], j);
                block_argmax(bv, bi);
                if (threadIdx.x == 0 && bi != 0x7fffffff)
                    __hip_atomic_fetch_max(&ws_pk[b * S + p], pack_vi(bv, bi),
                                           __ATOMIC_RELAXED, __HIP_MEMORY_SCOPE_AGENT);
            }
        }
    } else if (!greedy) {
        // ---- recovered argmax (redundant fr computation per block) ----
        int split = r - S * SPLIT_G;
        __shared__ int s_tok[MAXS];
        __shared__ unsigned char s_acc[MAXS];
        __shared__ int s_fr;
        int p = threadIdx.x;
        if (p < S) {
            int tok = draft_ids[b * S + p];
            s_tok[p] = tok;
            bool acc = false;
            if (tok != PLACEHOLDER) {
                float tp = target_probs[(size_t)b * (S + 1) * V + (size_t)p * V + tok];
                float dp = draft_probs[(size_t)b * S * V + (size_t)p * V + tok];
                acc = (tp / dp) >= uniform[b * S + p];
            }
            s_acc[p] = acc ? 1 : 0;
        }
        __syncthreads();
        if (threadIdx.x == 0) {
            int fr = -1;
            for (int q = 0; q < S; ++q) {
                if (s_tok[q] == PLACEHOLDER) break;
                if (!s_acc[q]) { fr = q; break; }
            }
            s_fr = fr;
            if (split == 0)
                __hip_atomic_store(&ws_fr[b], fr, __ATOMIC_RELAXED, __HIP_MEMORY_SCOPE_AGENT);
        }
        __syncthreads();
        int fr = s_fr;
        if (fr >= 0) {
            int chunk = ((V + SPLIT_R - 1) / SPLIT_R + 3) & ~3;
            int begin = split * chunk;
            int end = begin + chunk; if (end > V) end = V;
            if (begin < end) {
                const float* trow = target_probs + (size_t)b * (S + 1) * V + (size_t)fr * V;
                const float* drow = draft_probs + (size_t)b * S * V + (size_t)fr * V;
                const float* erow = exp_q + (size_t)b * V;
                float bv = 0.0f; int bi = 0x7fffffff;
                int vend = begin + ((end - begin) & ~3);
                const float4* t4 = (const float4*)trow;
                const float4* d4 = (const float4*)drow;
                const float4* e4 = (const float4*)erow;
                for (int j = (begin >> 2) + threadIdx.x; j < (vend >> 2); j += blockDim.x) {
                    float4 tt = t4[j], dd = d4[j], ee = e4[j];
                    int base = j << 2;
                    amax_combine(bv, bi, fmaxf(tt.x - dd.x, TINY_F) / ee.x, base);
                    amax_combine(bv, bi, fmaxf(tt.y - dd.y, TINY_F) / ee.y, base + 1);
                    amax_combine(bv, bi, fmaxf(tt.z - dd.z, TINY_F) / ee.z, base + 2);
                    amax_combine(bv, bi, fmaxf(tt.w - dd.w, TINY_F) / ee.w, base + 3);
                }
                for (int j = vend + threadIdx.x; j < end; j += blockDim.x)
                    amax_combine(bv, bi, fmaxf(trow[j] - drow[j], TINY_F) / erow[j], j);
                block_argmax(bv, bi);
                if (threadIdx.x == 0 && bi != 0x7fffffff)
                    __hip_atomic_fetch_max(&ws_pk[B * S + b], pack_vi(bv, bi),
                                           __ATOMIC_RELAXED, __HIP_MEMORY_SCOPE_AGENT);
            }
        }
    }

    // ---- last block of this row finalizes ----
    if (threadIdx.x == 0) {
        unsigned prev = __hip_atomic_fetch_add(&ws_cnt[b], 1u,
                                               __ATOMIC_ACQ_REL, __HIP_MEMORY_SCOPE_AGENT);
        if (prev == (unsigned)(per_row - 1)) {
            int ob = b * (S + 1);
            int toks[MAXS];
            for (int q = 0; q < S; ++q) toks[q] = draft_ids[b * S + q];

            if (greedy) {
                int ng = 0;
                bool rej = false;
                for (int q = 0; q < S; ++q) {
                    int tok = toks[q];
                    if (tok == PLACEHOLDER) break;
                    unsigned long long pk = __hip_atomic_load(&ws_pk[b * S + q],
                                                              __ATOMIC_RELAXED,
                                                              __HIP_MEMORY_SCOPE_AGENT);
                    int am = unpack_idx(pk);
                    bool acc = (tok == am);
                    out[ob + q] = acc ? tok : am;
                    ++ng;
                    if (!acc) { rej = true; break; }
                }
                for (int q = ng; q <= S; ++q) out[ob + q] = PLACEHOLDER;
                if (!rej) out[ob + ng] = bonus[b];
            } else {
                int fr = __hip_atomic_load(&ws_fr[b], __ATOMIC_RELAXED,
                                           __HIP_MEMORY_SCOPE_AGENT);
                if (fr < 0) {
                    int ng = 0;
                    for (int q = 0; q < S; ++q) {
                        if (toks[q] == PLACEHOLDER) break;
                        out[ob + q] = toks[q];
                        ++ng;
                    }
                    for (int q = ng; q <= S; ++q) out[ob + q] = PLACEHOLDER;
                    out[ob + ng] = bonus[b];
                } else {
                    for (int q = 0; q < fr; ++q) out[ob + q] = toks[q];
                    unsigned long long pk = __hip_atomic_load(&ws_pk[B * S + b],
                                                              __ATOMIC_RELAXED,
                                                              __HIP_MEMORY_SCOPE_AGENT);
                    out[ob + fr] = unpack_idx(pk);
                    for (int q = fr + 1; q <= S; ++q) out[ob + q] = PLACEHOLDER;
                    // rejected -> bonus slot stays PLACEHOLDER
                }
            }
        }
    }
}

extern "C" void kernel_launch(void* const* d_in, const int* in_sizes, int n_in,
                              void* d_out, int out_size, void* d_ws, size_t ws_size,
                              hipStream_t stream) {
    const int*   draft_ids    = (const int*)d_in[0];
    const float* draft_probs  = (const float*)d_in[1];
    const float* target_probs = (const float*)d_in[2];
    const int*   bonus        = (const int*)d_in[3];
    const float* uniform      = (const float*)d_in[4];
    const float* exp_q        = (const float*)d_in[5];
    const int*   is_greedy    = (const int*)d_in[6];

    int B = in_sizes[6];           // 128
    int S = in_sizes[4] / B;       // 8
    int V = in_sizes[5] / B;       // 32000

    unsigned long long* ws_pk = (unsigned long long*)d_ws;       // B*S + B
    unsigned int* ws_cnt = (unsigned int*)(ws_pk + B * S + B);   // B
    int* ws_fr = (int*)(ws_cnt + B);                             // B
    int* out   = (int*)d_out;

    size_t zero_bytes = (size_t)(B * S + B) * 8 + (size_t)B * 4; // ws_pk + ws_cnt
    hipMemsetAsync(d_ws, 0, zero_bytes, stream);

    int per_row = S * SPLIT_G + SPLIT_R;
    k_fused<<<B * per_row, 256, 0, stream>>>(draft_ids, draft_probs, target_probs,
                                             bonus, uniform, exp_q, is_greedy,
                                             ws_pk, ws_cnt, ws_fr, out, B, S, V);
}

// Round 4
// 22.271 us; speedup vs baseline: 12.0414x; 12.0414x over previous
//
#include <hip/hip_runtime.h>

#define PLACEHOLDER (-1)
#define TINY_F 1.17549435e-38f
#define MAXS 32
#define SPLIT_G 8
#define SPLIT_R 16

__device__ __forceinline__ void amax_combine(float& bv, int& bi, float v, int i) {
    // jnp.argmax: first occurrence wins ties -> prefer smaller index on equal value
    if (v > bv || (v == bv && i < bi)) { bv = v; bi = i; }
}

__device__ __forceinline__ unsigned long long pack_vi(float v, int i) {
    // positive floats order like their bit patterns; ~index gives min-index tie-break
    return ((unsigned long long)__float_as_uint(v) << 32) |
           (unsigned long long)(0xFFFFFFFFu - (unsigned)i);
}

__device__ __forceinline__ int unpack_idx(unsigned long long p) {
    return (int)(0xFFFFFFFFu - (unsigned)(p & 0xFFFFFFFFull));
}

// block-level argmax reduce; result valid on thread 0. Block-uniform control flow.
__device__ __forceinline__ void block_argmax(float& bv, int& bi) {
    for (int off = 32; off > 0; off >>= 1) {
        float ov = __shfl_down(bv, off, 64);
        int   oi = __shfl_down(bi, off, 64);
        amax_combine(bv, bi, ov, oi);
    }
    __shared__ float sv[8];
    __shared__ int   si[8];
    int lane = threadIdx.x & 63;
    int w    = threadIdx.x >> 6;
    if (lane == 0) { sv[w] = bv; si[w] = bi; }
    __syncthreads();
    if (threadIdx.x == 0) {
        int nw = (blockDim.x + 63) >> 6;
        for (int k = 1; k < nw; ++k) amax_combine(bv, bi, sv[k], si[k]);
    }
}

// Kernel 1: all heavy argmax scans. Partial results go to PRIVATE slots (plain
// stores, no init, no atomics). Blocks:
//   [0, B*S*SPLIT_G)          greedy-row target-argmax chunk  -> ws_g[(b*S+p)*SPLIT_G+split]
//   [B*S*SPLIT_G, +B*SPLIT_R) recovered-argmax chunk          -> ws_r[b*SPLIT_R+split]
// Recovered blocks recompute fr redundantly (cheap gathered loads).
__global__ void k_main(const float* __restrict__ target_probs,
                       const float* __restrict__ draft_probs,
                       const float* __restrict__ exp_q,
                       const int* __restrict__ draft_ids,
                       const float* __restrict__ uniform,
                       const int* __restrict__ is_greedy,
                       unsigned long long* __restrict__ ws_g,
                       unsigned long long* __restrict__ ws_r,
                       int B, int S, int V) {
    int total_g = B * S * SPLIT_G;

    if ((int)blockIdx.x < total_g) {
        int t = blockIdx.x;
        int split = t % SPLIT_G;
        int bp = t / SPLIT_G;
        int b = bp / S;
        if (!is_greedy[b]) return;
        if (draft_ids[bp] == PLACEHOLDER) return;
        int p = bp - b * S;

        int chunk = ((V + SPLIT_G - 1) / SPLIT_G + 3) & ~3;
        int begin = split * chunk;
        int end = begin + chunk; if (end > V) end = V;
        if (begin >= end) return;

        const float* row = target_probs + (size_t)b * (S + 1) * V + (size_t)p * V;
        float bv = 0.0f; int bi = 0x7fffffff;
        int vend = begin + ((end - begin) & ~3);
        const float4* r4 = (const float4*)row;
        for (int j = (begin >> 2) + threadIdx.x; j < (vend >> 2); j += blockDim.x) {
            float4 f = r4[j];
            int base = j << 2;
            amax_combine(bv, bi, f.x, base);
            amax_combine(bv, bi, f.y, base + 1);
            amax_combine(bv, bi, f.z, base + 2);
            amax_combine(bv, bi, f.w, base + 3);
        }
        for (int j = vend + threadIdx.x; j < end; j += blockDim.x)
            amax_combine(bv, bi, row[j], j);
        block_argmax(bv, bi);
        if (threadIdx.x == 0) ws_g[(size_t)bp * SPLIT_G + split] = pack_vi(bv, bi);
    } else {
        int t = blockIdx.x - total_g;
        int split = t % SPLIT_R;
        int b = t / SPLIT_R;
        if (is_greedy[b]) return;

        // redundant fr computation (block-uniform result via LDS)
        __shared__ int s_tok[MAXS];
        __shared__ unsigned char s_acc[MAXS];
        __shared__ int s_fr;
        int p = threadIdx.x;
        if (p < S) {
            int tok = draft_ids[b * S + p];
            s_tok[p] = tok;
            bool acc = false;
            if (tok != PLACEHOLDER) {
                float tp = target_probs[(size_t)b * (S + 1) * V + (size_t)p * V + tok];
                float dp = draft_probs[(size_t)b * S * V + (size_t)p * V + tok];
                acc = (tp / dp) >= uniform[b * S + p];
            }
            s_acc[p] = acc ? 1 : 0;
        }
        __syncthreads();
        if (threadIdx.x == 0) {
            int fr = -1;
            for (int q = 0; q < S; ++q) {
                if (s_tok[q] == PLACEHOLDER) break;
                if (!s_acc[q]) { fr = q; break; }
            }
            s_fr = fr;
        }
        __syncthreads();
        int fr = s_fr;
        if (fr < 0) return;

        int chunk = ((V + SPLIT_R - 1) / SPLIT_R + 3) & ~3;
        int begin = split * chunk;
        int end = begin + chunk; if (end > V) end = V;
        if (begin >= end) return;

        const float* trow = target_probs + (size_t)b * (S + 1) * V + (size_t)fr * V;
        const float* drow = draft_probs + (size_t)b * S * V + (size_t)fr * V;
        const float* erow = exp_q + (size_t)b * V;
        float bv = 0.0f; int bi = 0x7fffffff;
        int vend = begin + ((end - begin) & ~3);
        const float4* t4 = (const float4*)trow;
        const float4* d4 = (const float4*)drow;
        const float4* e4 = (const float4*)erow;
        for (int j = (begin >> 2) + threadIdx.x; j < (vend >> 2); j += blockDim.x) {
            float4 tt = t4[j], dd = d4[j], ee = e4[j];
            int base = j << 2;
            amax_combine(bv, bi, fmaxf(tt.x - dd.x, TINY_F) / ee.x, base);
            amax_combine(bv, bi, fmaxf(tt.y - dd.y, TINY_F) / ee.y, base + 1);
            amax_combine(bv, bi, fmaxf(tt.z - dd.z, TINY_F) / ee.z, base + 2);
            amax_combine(bv, bi, fmaxf(tt.w - dd.w, TINY_F) / ee.w, base + 3);
        }
        for (int j = vend + threadIdx.x; j < end; j += blockDim.x)
            amax_combine(bv, bi, fmaxf(trow[j] - drow[j], TINY_F) / erow[j], j);
        block_argmax(bv, bi);
        if (threadIdx.x == 0) ws_r[(size_t)b * SPLIT_R + split] = pack_vi(bv, bi);
    }
}

// Kernel 2: one wave per row. Merge partials, redo accept scan, assemble output.
__global__ void k_final(const int* __restrict__ draft_ids,
                        const float* __restrict__ draft_probs,
                        const float* __restrict__ target_probs,
                        const int* __restrict__ bonus,
                        const float* __restrict__ uniform,
                        const int* __restrict__ is_greedy,
                        const unsigned long long* __restrict__ ws_g,
                        const unsigned long long* __restrict__ ws_r,
                        int* __restrict__ out,
                        int B, int S, int V) {
    int b = blockIdx.x;
    int lane = threadIdx.x;            // 64 threads = 1 wave
    bool greedy = is_greedy[b] != 0;

    __shared__ int s_tok[MAXS];
    __shared__ int s_rep[MAXS];
    __shared__ unsigned char s_acc[MAXS];

    if (lane < S) {
        int tok = draft_ids[b * S + lane];
        s_tok[lane] = tok;
        bool acc = false; int rep = 0;
        if (tok != PLACEHOLDER) {
            if (greedy) {
                unsigned long long m = 0ull;
                const unsigned long long* g = ws_g + (size_t)(b * S + lane) * SPLIT_G;
                int chunk = ((V + SPLIT_G - 1) / SPLIT_G + 3) & ~3;
                for (int k = 0; k < SPLIT_G; ++k) {
                    int begin = k * chunk;
                    if (begin < V) { unsigned long long x = g[k]; if (x > m) m = x; }
                }
                rep = unpack_idx(m);
                acc = (tok == rep);
            } else {
                float tp = target_probs[(size_t)b * (S + 1) * V + (size_t)lane * V + tok];
                float dp = draft_probs[(size_t)b * S * V + (size_t)lane * V + tok];
                acc = (tp / dp) >= uniform[b * S + lane];
            }
        }
        s_acc[lane] = acc ? 1 : 0;
        s_rep[lane] = rep;
    }

    // recovered merge (meaningful only for non-greedy rejected rows; reading
    // unwritten slots is harmless — result unused in that case)
    unsigned long long rm = 0ull;
    if (!greedy && lane < SPLIT_R) {
        int chunk = ((V + SPLIT_R - 1) / SPLIT_R + 3) & ~3;
        if (lane * chunk < V) rm = ws_r[(size_t)b * SPLIT_R + lane];
    }
    for (int off = 8; off > 0; off >>= 1) {
        unsigned long long o = __shfl_down(rm, off, 64);
        if (o > rm) rm = o;
    }
    __syncthreads();

    if (lane == 0) {
        int ob = b * (S + 1);
        int ng = 0;
        bool rej = false;
        for (int p = 0; p < S; ++p) {
            int tok = s_tok[p];
            if (tok == PLACEHOLDER) break;
            bool acc = s_acc[p] != 0;
            out[ob + p] = acc ? tok : (greedy ? s_rep[p] : unpack_idx(rm));
            ++ng;
            if (!acc) { rej = true; break; }
        }
        for (int p = ng; p <= S; ++p) out[ob + p] = PLACEHOLDER;
        if (!rej) out[ob + ng] = bonus[b];
    }
}

extern "C" void kernel_launch(void* const* d_in, const int* in_sizes, int n_in,
                              void* d_out, int out_size, void* d_ws, size_t ws_size,
                              hipStream_t stream) {
    const int*   draft_ids    = (const int*)d_in[0];
    const float* draft_probs  = (const float*)d_in[1];
    const float* target_probs = (const float*)d_in[2];
    const int*   bonus        = (const int*)d_in[3];
    const float* uniform      = (const float*)d_in[4];
    const float* exp_q        = (const float*)d_in[5];
    const int*   is_greedy    = (const int*)d_in[6];

    int B = in_sizes[6];           // 128
    int S = in_sizes[4] / B;       // 8
    int V = in_sizes[5] / B;       // 32000

    unsigned long long* ws_g = (unsigned long long*)d_ws;        // B*S*SPLIT_G
    unsigned long long* ws_r = ws_g + (size_t)B * S * SPLIT_G;   // B*SPLIT_R
    int* out = (int*)d_out;

    int grid = B * S * SPLIT_G + B * SPLIT_R;
    k_main<<<grid, 256, 0, stream>>>(target_probs, draft_probs, exp_q, draft_ids,
                                     uniform, is_greedy, ws_g, ws_r, B, S, V);
    k_final<<<B, 64, 0, stream>>>(draft_ids, draft_probs, target_probs, bonus,
                                  uniform, is_greedy, ws_g, ws_r, out, B, S, V);
}

// Round 5
// 16.297 us; speedup vs baseline: 16.4551x; 1.3665x over previous
//
#include <hip/hip_runtime.h>

#define PLACEHOLDER (-1)
#define TINY_F 1.17549435e-38f
#define MAXS 32
#define SPLIT_G 8
#define SPLIT_R 16

__device__ __forceinline__ void amax_combine(float& bv, int& bi, float v, int i) {
    // jnp.argmax: first occurrence wins ties -> prefer smaller index on equal value
    if (v > bv || (v == bv && i < bi)) { bv = v; bi = i; }
}

__device__ __forceinline__ unsigned long long pack_vi(float v, int i) {
    // positive floats order like their bit patterns; ~index gives min-index tie-break
    return ((unsigned long long)__float_as_uint(v) << 32) |
           (unsigned long long)(0xFFFFFFFFu - (unsigned)i);
}

__device__ __forceinline__ int unpack_idx(unsigned long long p) {
    return (int)(0xFFFFFFFFu - (unsigned)(p & 0xFFFFFFFFull));
}

// block-level argmax reduce; result valid on thread 0. All threads must reach it.
__device__ __forceinline__ void block_argmax(float& bv, int& bi) {
    for (int off = 32; off > 0; off >>= 1) {
        float ov = __shfl_down(bv, off, 64);
        int   oi = __shfl_down(bi, off, 64);
        amax_combine(bv, bi, ov, oi);
    }
    __shared__ float sv[8];
    __shared__ int   si[8];
    int lane = threadIdx.x & 63;
    int w    = threadIdx.x >> 6;
    if (lane == 0) { sv[w] = bv; si[w] = bi; }
    __syncthreads();
    if (threadIdx.x == 0) {
        int nw = (blockDim.x + 63) >> 6;
        for (int k = 1; k < nw; ++k) amax_combine(bv, bi, sv[k], si[k]);
    }
}

// Kernel 1: parallel scans, private-slot outputs (plain stores, no init/atomics).
//   blocks [0, B*SPLIT_G)        : greedy-row target-argmax at p=0 ONLY
//   blocks [B*SPLIT_G, +B*SPLIT_R): recovered-argmax chunk (redundant fr per block)
// Greedy p>0 argmaxes (needed only if a greedy row accepts at p=0; ~1/V chance)
// are handled by k_final's cold path.
__global__ void k_main(const float* __restrict__ target_probs,
                       const float* __restrict__ draft_probs,
                       const float* __restrict__ exp_q,
                       const int* __restrict__ draft_ids,
                       const float* __restrict__ uniform,
                       const int* __restrict__ is_greedy,
                       unsigned long long* __restrict__ ws_g,   // B*SPLIT_G
                       unsigned long long* __restrict__ ws_r,   // B*SPLIT_R
                       int B, int S, int V) {
    int total_g = B * SPLIT_G;

    if ((int)blockIdx.x < total_g) {
        int b = blockIdx.x / SPLIT_G;
        int split = blockIdx.x - b * SPLIT_G;
        if (!is_greedy[b]) return;
        if (draft_ids[b * S] == PLACEHOLDER) return;

        int chunk = ((V + SPLIT_G - 1) / SPLIT_G + 3) & ~3;
        int begin = split * chunk;
        int end = begin + chunk; if (end > V) end = V;
        if (begin >= end) return;

        const float* row = target_probs + (size_t)b * (S + 1) * V;  // p = 0
        float bv = 0.0f; int bi = 0x7fffffff;
        int vend = begin + ((end - begin) & ~3);
        const float4* r4 = (const float4*)row;
        for (int j = (begin >> 2) + threadIdx.x; j < (vend >> 2); j += blockDim.x) {
            float4 f = r4[j];
            int base = j << 2;
            amax_combine(bv, bi, f.x, base);
            amax_combine(bv, bi, f.y, base + 1);
            amax_combine(bv, bi, f.z, base + 2);
            amax_combine(bv, bi, f.w, base + 3);
        }
        for (int j = vend + threadIdx.x; j < end; j += blockDim.x)
            amax_combine(bv, bi, row[j], j);
        block_argmax(bv, bi);
        if (threadIdx.x == 0) ws_g[(size_t)b * SPLIT_G + split] = pack_vi(bv, bi);
    } else {
        int t = blockIdx.x - total_g;
        int split = t % SPLIT_R;
        int b = t / SPLIT_R;
        if (is_greedy[b]) return;

        // redundant first-reject computation (block-uniform via LDS)
        __shared__ int s_tok[MAXS];
        __shared__ unsigned char s_acc[MAXS];
        __shared__ int s_fr;
        int p = threadIdx.x;
        if (p < S) {
            int tok = draft_ids[b * S + p];
            s_tok[p] = tok;
            bool acc = false;
            if (tok != PLACEHOLDER) {
                float tp = target_probs[(size_t)b * (S + 1) * V + (size_t)p * V + tok];
                float dp = draft_probs[(size_t)b * S * V + (size_t)p * V + tok];
                acc = (tp / dp) >= uniform[b * S + p];
            }
            s_acc[p] = acc ? 1 : 0;
        }
        __syncthreads();
        if (threadIdx.x == 0) {
            int fr = -1;
            for (int q = 0; q < S; ++q) {
                if (s_tok[q] == PLACEHOLDER) break;
                if (!s_acc[q]) { fr = q; break; }
            }
            s_fr = fr;
        }
        __syncthreads();
        int fr = s_fr;
        if (fr < 0) return;

        int chunk = ((V + SPLIT_R - 1) / SPLIT_R + 3) & ~3;
        int begin = split * chunk;
        int end = begin + chunk; if (end > V) end = V;
        if (begin >= end) return;

        const float* trow = target_probs + (size_t)b * (S + 1) * V + (size_t)fr * V;
        const float* drow = draft_probs + (size_t)b * S * V + (size_t)fr * V;
        const float* erow = exp_q + (size_t)b * V;
        float bv = 0.0f; int bi = 0x7fffffff;
        int vend = begin + ((end - begin) & ~3);
        const float4* t4 = (const float4*)trow;
        const float4* d4 = (const float4*)drow;
        const float4* e4 = (const float4*)erow;
        for (int j = (begin >> 2) + threadIdx.x; j < (vend >> 2); j += blockDim.x) {
            float4 tt = t4[j], dd = d4[j], ee = e4[j];
            int base = j << 2;
            amax_combine(bv, bi, fmaxf(tt.x - dd.x, TINY_F) / ee.x, base);
            amax_combine(bv, bi, fmaxf(tt.y - dd.y, TINY_F) / ee.y, base + 1);
            amax_combine(bv, bi, fmaxf(tt.z - dd.z, TINY_F) / ee.z, base + 2);
            amax_combine(bv, bi, fmaxf(tt.w - dd.w, TINY_F) / ee.w, base + 3);
        }
        for (int j = vend + threadIdx.x; j < end; j += blockDim.x)
            amax_combine(bv, bi, fmaxf(trow[j] - drow[j], TINY_F) / erow[j], j);
        block_argmax(bv, bi);
        if (threadIdx.x == 0) ws_r[(size_t)b * SPLIT_R + split] = pack_vi(bv, bi);
    }
}

// Kernel 2: one 256-thread block per row. Merge partials, assemble output.
// Greedy rows that accept at p=0 (rare) fall into a block-wide scan loop.
__global__ void k_final(const int* __restrict__ draft_ids,
                        const float* __restrict__ draft_probs,
                        const float* __restrict__ target_probs,
                        const int* __restrict__ bonus,
                        const float* __restrict__ uniform,
                        const int* __restrict__ is_greedy,
                        const unsigned long long* __restrict__ ws_g,
                        const unsigned long long* __restrict__ ws_r,
                        int* __restrict__ out,
                        int B, int S, int V) {
    int b = blockIdx.x;
    int tid = threadIdx.x;
    bool greedy = is_greedy[b] != 0;
    int ob = b * (S + 1);

    __shared__ int s_am;

    if (greedy) {
        int p = 0, ng = 0;
        bool rej = false;
        while (p < S) {
            int tok = draft_ids[b * S + p];   // block-uniform
            if (tok == PLACEHOLDER) break;
            __syncthreads();                   // protect s_am WAR across iterations
            if (p == 0) {
                if (tid == 0) {
                    unsigned long long m = 0ull;
                    const unsigned long long* g = ws_g + (size_t)b * SPLIT_G;
                    int chunk = ((V + SPLIT_G - 1) / SPLIT_G + 3) & ~3;
                    for (int k = 0; k < SPLIT_G; ++k)
                        if (k * chunk < V) { unsigned long long x = g[k]; if (x > m) m = x; }
                    s_am = unpack_idx(m);
                }
            } else {
                // cold path: block-wide argmax of target row p
                const float* row = target_probs + (size_t)b * (S + 1) * V + (size_t)p * V;
                float bv = 0.0f; int bi = 0x7fffffff;
                int nv4 = V >> 2;
                const float4* r4 = (const float4*)row;
                for (int j = tid; j < nv4; j += blockDim.x) {
                    float4 f = r4[j];
                    int base = j << 2;
                    amax_combine(bv, bi, f.x, base);
                    amax_combine(bv, bi, f.y, base + 1);
                    amax_combine(bv, bi, f.z, base + 2);
                    amax_combine(bv, bi, f.w, base + 3);
                }
                for (int j = (nv4 << 2) + tid; j < V; j += blockDim.x)
                    amax_combine(bv, bi, row[j], j);
                block_argmax(bv, bi);
                if (tid == 0) s_am = bi;
            }
            __syncthreads();
            int am = s_am;
            bool acc = (tok == am);
            if (tid == 0) out[ob + p] = acc ? tok : am;
            ++ng;
            if (!acc) { rej = true; break; }
            ++p;
        }
        if (tid == 0) {
            for (int q = ng; q <= S; ++q) out[ob + q] = PLACEHOLDER;
            if (!rej) out[ob + ng] = bonus[b];
        }
    } else {
        __shared__ int s_tok[MAXS];
        __shared__ unsigned char s_acc[MAXS];
        if (tid < S) {
            int tok = draft_ids[b * S + tid];
            s_tok[tid] = tok;
            bool acc = false;
            if (tok != PLACEHOLDER) {
                float tp = target_probs[(size_t)b * (S + 1) * V + (size_t)tid * V + tok];
                float dp = draft_probs[(size_t)b * S * V + (size_t)tid * V + tok];
                acc = (tp / dp) >= uniform[b * S + tid];
            }
            s_acc[tid] = acc ? 1 : 0;
        }
        __syncthreads();
        if (tid == 0) {
            // merge recovered partials (only used if a reject exists)
            unsigned long long rm = 0ull;
            const unsigned long long* r = ws_r + (size_t)b * SPLIT_R;
            int chunk = ((V + SPLIT_R - 1) / SPLIT_R + 3) & ~3;

            int ng = 0;
            bool rej = false;
            for (int p = 0; p < S; ++p) {
                int tok = s_tok[p];
                if (tok == PLACEHOLDER) break;
                bool acc = s_acc[p] != 0;
                if (acc) {
                    out[ob + p] = tok;
                    ++ng;
                } else {
                    for (int k = 0; k < SPLIT_R; ++k)
                        if (k * chunk < V) { unsigned long long x = r[k]; if (x > rm) rm = x; }
                    out[ob + p] = unpack_idx(rm);
                    ++ng;
                    rej = true;
                    break;
                }
            }
            for (int q = ng; q <= S; ++q) out[ob + q] = PLACEHOLDER;
            if (!rej) out[ob + ng] = bonus[b];
        }
    }
}

extern "C" void kernel_launch(void* const* d_in, const int* in_sizes, int n_in,
                              void* d_out, int out_size, void* d_ws, size_t ws_size,
                              hipStream_t stream) {
    const int*   draft_ids    = (const int*)d_in[0];
    const float* draft_probs  = (const float*)d_in[1];
    const float* target_probs = (const float*)d_in[2];
    const int*   bonus        = (const int*)d_in[3];
    const float* uniform      = (const float*)d_in[4];
    const float* exp_q        = (const float*)d_in[5];
    const int*   is_greedy    = (const int*)d_in[6];

    int B = in_sizes[6];           // 128
    int S = in_sizes[4] / B;       // 8
    int V = in_sizes[5] / B;       // 32000

    unsigned long long* ws_g = (unsigned long long*)d_ws;      // B*SPLIT_G
    unsigned long long* ws_r = ws_g + (size_t)B * SPLIT_G;     // B*SPLIT_R
    int* out = (int*)d_out;

    int grid = B * SPLIT_G + B * SPLIT_R;
    k_main<<<grid, 256, 0, stream>>>(target_probs, draft_probs, exp_q, draft_ids,
                                     uniform, is_greedy, ws_g, ws_r, B, S, V);
    k_final<<<B, 256, 0, stream>>>(draft_ids, draft_probs, target_probs, bonus,
                                   uniform, is_greedy, ws_g, ws_r, out, B, S, V);
}

// Round 6
// 15.209 us; speedup vs baseline: 17.6330x; 1.0716x over previous
//
#include <hip/hip_runtime.h>

#define PLACEHOLDER (-1)
#define TINY_F 1.17549435e-38f
#define MAXS 32
#define SPLIT_G 8
#define SPLIT_R 16

__device__ __forceinline__ void amax_combine(float& bv, int& bi, float v, int i) {
    // jnp.argmax: first occurrence wins ties -> prefer smaller index on equal value
    if (v > bv || (v == bv && i < bi)) { bv = v; bi = i; }
}

__device__ __forceinline__ unsigned long long pack_vi(float v, int i) {
    // positive floats order like their bit patterns; ~index gives min-index tie-break
    return ((unsigned long long)__float_as_uint(v) << 32) |
           (unsigned long long)(0xFFFFFFFFu - (unsigned)i);
}

__device__ __forceinline__ int unpack_idx(unsigned long long p) {
    return (int)(0xFFFFFFFFu - (unsigned)(p & 0xFFFFFFFFull));
}

// 256-thread block argmax; result on thread 0. Block-uniform control flow.
__device__ __forceinline__ void block_argmax(float& bv, int& bi) {
    for (int off = 32; off > 0; off >>= 1) {
        float ov = __shfl_down(bv, off, 64);
        int   oi = __shfl_down(bi, off, 64);
        amax_combine(bv, bi, ov, oi);
    }
    __shared__ float sv[8];
    __shared__ int   si[8];
    int lane = threadIdx.x & 63;
    int w    = threadIdx.x >> 6;
    if (lane == 0) { sv[w] = bv; si[w] = bi; }
    __syncthreads();
    if (threadIdx.x == 0) {
        int nw = (blockDim.x + 63) >> 6;
        for (int k = 1; k < nw; ++k) amax_combine(bv, bi, sv[k], si[k]);
    }
}

// single-wave (64-lane) argmax with broadcast to all lanes
__device__ __forceinline__ void wave_argmax_bcast(float& bv, int& bi) {
    for (int off = 32; off > 0; off >>= 1) {
        float ov = __shfl_down(bv, off, 64);
        int   oi = __shfl_down(bi, off, 64);
        amax_combine(bv, bi, ov, oi);
    }
    bv = __shfl(bv, 0, 64);
    bi = __shfl(bi, 0, 64);
}

// Kernel 1: parallel scans, private-slot partials (plain stores, no atomics).
//   blocks [0, B*SPLIT_G)         : greedy-row target-argmax at p=0 only
//   blocks [B*SPLIT_G, +B*SPLIT_R): recovered-argmax chunk; split 0 additionally
//                                   writes ws_fr + the full non-greedy output row.
// Greedy p>0 argmaxes (only needed if a greedy row accepts at p=0; ~1/V chance)
// are handled by k_final's cold path.
__global__ void k_main(const float* __restrict__ target_probs,
                       const float* __restrict__ draft_probs,
                       const float* __restrict__ exp_q,
                       const int* __restrict__ draft_ids,
                       const float* __restrict__ uniform,
                       const int* __restrict__ bonus,
                       const int* __restrict__ is_greedy,
                       unsigned long long* __restrict__ ws_g,   // B*SPLIT_G
                       unsigned long long* __restrict__ ws_r,   // B*SPLIT_R
                       int* __restrict__ ws_fr,                 // B
                       int* __restrict__ out,
                       int B, int S, int V) {
    int total_g = B * SPLIT_G;

    if ((int)blockIdx.x < total_g) {
        int b = blockIdx.x / SPLIT_G;
        int split = blockIdx.x - b * SPLIT_G;
        if (!is_greedy[b]) return;
        if (draft_ids[b * S] == PLACEHOLDER) return;

        int chunk = ((V + SPLIT_G - 1) / SPLIT_G + 3) & ~3;
        int begin = split * chunk;
        int end = begin + chunk; if (end > V) end = V;
        if (begin >= end) return;

        const float* row = target_probs + (size_t)b * (S + 1) * V;  // p = 0
        float bv = 0.0f; int bi = 0x7fffffff;
        int vend = begin + ((end - begin) & ~3);
        const float4* r4 = (const float4*)row;
        for (int j = (begin >> 2) + threadIdx.x; j < (vend >> 2); j += blockDim.x) {
            float4 f = r4[j];
            int base = j << 2;
            amax_combine(bv, bi, f.x, base);
            amax_combine(bv, bi, f.y, base + 1);
            amax_combine(bv, bi, f.z, base + 2);
            amax_combine(bv, bi, f.w, base + 3);
        }
        for (int j = vend + threadIdx.x; j < end; j += blockDim.x)
            amax_combine(bv, bi, row[j], j);
        block_argmax(bv, bi);
        if (threadIdx.x == 0) ws_g[(size_t)b * SPLIT_G + split] = pack_vi(bv, bi);
    } else {
        int t = blockIdx.x - total_g;
        int split = t % SPLIT_R;
        int b = t / SPLIT_R;
        if (is_greedy[b]) return;

        int chunk = ((V + SPLIT_R - 1) / SPLIT_R + 3) & ~3;
        int begin = split * chunk;
        int end = begin + chunk; if (end > V) end = V;
        bool has_work = begin < end;

        // --- prefetch exp_q chunk (fr-independent addresses) into registers ---
        const float* erow = exp_q + (size_t)b * V;
        int nj = has_work ? (((end - begin) & ~3) >> 2) : 0;  // # float4 in chunk
        const float4* e4 = (const float4*)(erow + begin);
        int tid = threadIdx.x;
        float4 ea = make_float4(0.f, 0.f, 0.f, 0.f), eb = ea;
        if (tid < nj) ea = e4[tid];
        if (tid + (int)blockDim.x < nj) eb = e4[tid + blockDim.x];

        // --- redundant first-reject computation (block-uniform via LDS) ---
        __shared__ int s_tok[MAXS];
        __shared__ unsigned char s_acc[MAXS];
        __shared__ int s_fr;
        if (tid < S) {
            int tok = draft_ids[b * S + tid];
            s_tok[tid] = tok;
            bool acc = false;
            if (tok != PLACEHOLDER) {
                float tp = target_probs[(size_t)b * (S + 1) * V + (size_t)tid * V + tok];
                float dp = draft_probs[(size_t)b * S * V + (size_t)tid * V + tok];
                acc = (tp / dp) >= uniform[b * S + tid];
            }
            s_acc[tid] = acc ? 1 : 0;
        }
        __syncthreads();
        if (tid == 0) {
            int fr = -1;
            for (int q = 0; q < S; ++q) {
                if (s_tok[q] == PLACEHOLDER) break;
                if (!s_acc[q]) { fr = q; break; }
            }
            s_fr = fr;
        }
        __syncthreads();
        int fr = s_fr;

        // --- split 0 finalizes the non-greedy output row ---
        if (split == 0 && tid == 0) {
            ws_fr[b] = fr;
            int ob = b * (S + 1);
            if (fr < 0) {
                int ng = 0;
                for (int p = 0; p < S; ++p) {
                    if (s_tok[p] == PLACEHOLDER) break;
                    out[ob + p] = s_tok[p];
                    ++ng;
                }
                for (int q = ng; q <= S; ++q) out[ob + q] = PLACEHOLDER;
                out[ob + ng] = bonus[b];
            } else {
                for (int p = 0; p < fr; ++p) out[ob + p] = s_tok[p];
                for (int q = fr; q <= S; ++q) out[ob + q] = PLACEHOLDER;
                // out[ob+fr] patched by k_final; bonus slot stays PLACEHOLDER
            }
        }
        if (fr < 0 || !has_work) return;

        // --- recovered-argmax scan of this chunk ---
        const float* trow = target_probs + (size_t)b * (S + 1) * V + (size_t)fr * V;
        const float* drow = draft_probs + (size_t)b * S * V + (size_t)fr * V;
        const float4* t4 = (const float4*)(trow + begin);
        const float4* d4 = (const float4*)(drow + begin);
        float bv = 0.0f; int bi = 0x7fffffff;
        if (tid < nj) {
            float4 tt = t4[tid], dd = d4[tid];
            int base = begin + (tid << 2);
            amax_combine(bv, bi, fmaxf(tt.x - dd.x, TINY_F) / ea.x, base);
            amax_combine(bv, bi, fmaxf(tt.y - dd.y, TINY_F) / ea.y, base + 1);
            amax_combine(bv, bi, fmaxf(tt.z - dd.z, TINY_F) / ea.z, base + 2);
            amax_combine(bv, bi, fmaxf(tt.w - dd.w, TINY_F) / ea.w, base + 3);
        }
        if (tid + (int)blockDim.x < nj) {
            int j = tid + blockDim.x;
            float4 tt = t4[j], dd = d4[j];
            int base = begin + (j << 2);
            amax_combine(bv, bi, fmaxf(tt.x - dd.x, TINY_F) / eb.x, base);
            amax_combine(bv, bi, fmaxf(tt.y - dd.y, TINY_F) / eb.y, base + 1);
            amax_combine(bv, bi, fmaxf(tt.z - dd.z, TINY_F) / eb.z, base + 2);
            amax_combine(bv, bi, fmaxf(tt.w - dd.w, TINY_F) / eb.w, base + 3);
        }
        for (int j = tid + 2 * blockDim.x; j < nj; j += blockDim.x) {  // generic spill
            float4 tt = t4[j], dd = d4[j], ee = e4[j];
            int base = begin + (j << 2);
            amax_combine(bv, bi, fmaxf(tt.x - dd.x, TINY_F) / ee.x, base);
            amax_combine(bv, bi, fmaxf(tt.y - dd.y, TINY_F) / ee.y, base + 1);
            amax_combine(bv, bi, fmaxf(tt.z - dd.z, TINY_F) / ee.z, base + 2);
            amax_combine(bv, bi, fmaxf(tt.w - dd.w, TINY_F) / ee.w, base + 3);
        }
        for (int j = begin + (nj << 2) + tid; j < end; j += blockDim.x)  // scalar tail
            amax_combine(bv, bi, fmaxf(trow[j] - drow[j], TINY_F) / erow[j], j);
        block_argmax(bv, bi);
        if (tid == 0) ws_r[(size_t)b * SPLIT_R + split] = pack_vi(bv, bi);
    }
}

// Kernel 2: one wave per row. Greedy rows: merge p=0 partials + assemble row
// (cold-path full scans for p>0 if ever needed). Non-greedy: patch one token.
__global__ void k_final(const int* __restrict__ draft_ids,
                        const float* __restrict__ target_probs,
                        const int* __restrict__ bonus,
                        const int* __restrict__ is_greedy,
                        const unsigned long long* __restrict__ ws_g,
                        const unsigned long long* __restrict__ ws_r,
                        const int* __restrict__ ws_fr,
                        int* __restrict__ out,
                        int B, int S, int V) {
    int b = blockIdx.x;
    int lane = threadIdx.x;            // 64 threads = 1 wave
    int ob = b * (S + 1);

    if (is_greedy[b]) {
        // merge p=0 partials across lanes
        unsigned long long gm = 0ull;
        {
            int chunk = ((V + SPLIT_G - 1) / SPLIT_G + 3) & ~3;
            if (lane < SPLIT_G && lane * chunk < V)
                gm = ws_g[(size_t)b * SPLIT_G + lane];
        }
        for (int off = SPLIT_G / 2; off > 0; off >>= 1) {
            unsigned long long o = __shfl_down(gm, off, 64);
            if (o > gm) gm = o;
        }
        gm = __shfl(gm, 0, 64);
        int am0 = unpack_idx(gm);

        int p = 0, ng = 0;
        bool rej = false;
        while (p < S) {
            int tok = draft_ids[b * S + p];
            if (tok == PLACEHOLDER) break;
            int am;
            if (p == 0) {
                am = am0;
            } else {
                // cold path (greedy row accepted at all earlier positions)
                const float* row = target_probs + (size_t)b * (S + 1) * V + (size_t)p * V;
                float bv = 0.0f; int bi = 0x7fffffff;
                int nv4 = V >> 2;
                const float4* r4 = (const float4*)row;
                for (int j = lane; j < nv4; j += 64) {
                    float4 f = r4[j];
                    int base = j << 2;
                    amax_combine(bv, bi, f.x, base);
                    amax_combine(bv, bi, f.y, base + 1);
                    amax_combine(bv, bi, f.z, base + 2);
                    amax_combine(bv, bi, f.w, base + 3);
                }
                for (int j = (nv4 << 2) + lane; j < V; j += 64)
                    amax_combine(bv, bi, row[j], j);
                wave_argmax_bcast(bv, bi);
                am = bi;
            }
            bool acc = (tok == am);
            if (lane == 0) out[ob + p] = acc ? tok : am;
            ++ng;
            if (!acc) { rej = true; break; }
            ++p;
        }
        if (lane == 0) {
            for (int q = ng; q <= S; ++q) out[ob + q] = PLACEHOLDER;
            if (!rej) out[ob + ng] = bonus[b];
        }
    } else {
        int fr = ws_fr[b];
        if (fr < 0) return;   // row fully written by k_main
        unsigned long long rm = 0ull;
        {
            int chunk = ((V + SPLIT_R - 1) / SPLIT_R + 3) & ~3;
            if (lane < SPLIT_R && lane * chunk < V)
                rm = ws_r[(size_t)b * SPLIT_R + lane];
        }
        for (int off = SPLIT_R / 2; off > 0; off >>= 1) {
            unsigned long long o = __shfl_down(rm, off, 64);
            if (o > rm) rm = o;
        }
        if (lane == 0) out[ob + fr] = unpack_idx(rm);
    }
}

extern "C" void kernel_launch(void* const* d_in, const int* in_sizes, int n_in,
                              void* d_out, int out_size, void* d_ws, size_t ws_size,
                              hipStream_t stream) {
    const int*   draft_ids    = (const int*)d_in[0];
    const float* draft_probs  = (const float*)d_in[1];
    const float* target_probs = (const float*)d_in[2];
    const int*   bonus        = (const int*)d_in[3];
    const float* uniform      = (const float*)d_in[4];
    const float* exp_q        = (const float*)d_in[5];
    const int*   is_greedy    = (const int*)d_in[6];

    int B = in_sizes[6];           // 128
    int S = in_sizes[4] / B;       // 8
    int V = in_sizes[5] / B;       // 32000

    unsigned long long* ws_g = (unsigned long long*)d_ws;      // B*SPLIT_G
    unsigned long long* ws_r = ws_g + (size_t)B * SPLIT_G;     // B*SPLIT_R
    int* ws_fr = (int*)(ws_r + (size_t)B * SPLIT_R);           // B
    int* out = (int*)d_out;

    int grid = B * SPLIT_G + B * SPLIT_R;
    k_main<<<grid, 256, 0, stream>>>(target_probs, draft_probs, exp_q, draft_ids,
                                     uniform, bonus, is_greedy,
                                     ws_g, ws_r, ws_fr, out, B, S, V);
    k_final<<<B, 64, 0, stream>>>(draft_ids, target_probs, bonus, is_greedy,
                                  ws_g, ws_r, ws_fr, out, B, S, V);
}